// Round 17
// baseline (108.985 us; speedup 1.0000x reference)
//
#include <hip/hip_runtime.h>
#include <hip/hip_bf16.h>

// ---- problem constants ----
#define BATCH   4096
#define FEAT    1024
#define NTREES  10
#define NNODES  255
#define NLEAF   256
#define NCLS    1000
#define KTOT    2560          // NTREES*NLEAF

typedef __attribute__((ext_vector_type(8))) short  bf16x8;
typedef __attribute__((ext_vector_type(4))) float  f32x4;

// fp8 scales: route stored as fp8(route*64); P stored as fp8(P*0.1*4096)
#define DEQ (1.0f / 262144.0f)

// workspace layout (bytes)
#define OFF_XB 0u             // xb bf16 [4096][1024]      8,388,608
#define OFF_WT 8388608u       // wT bf16 [10][256][1024]   5,242,880
#define OFF_PT 13631488u      // pT8 fp8 [1024][2560]      2,621,440
#define OFF_RT 16252928u      // route8 fp8 [4096][2560]  10,485,760

#define WAITVM(N) asm volatile("s_waitcnt vmcnt(" #N ")" ::: "memory")
#define WAITLGKM() asm volatile("s_waitcnt lgkmcnt(0)" ::: "memory")
#define BAR() __builtin_amdgcn_s_barrier()

__device__ __forceinline__ void load_lds16(const void* g, void* l) {
    __builtin_amdgcn_global_load_lds(
        (const __attribute__((address_space(1))) unsigned int*)g,
        (__attribute__((address_space(3))) unsigned int*)l, 16, 0, 0);
}

__device__ __forceinline__ unsigned short pk_fp8(float a, float b) {
    int r = __builtin_amdgcn_cvt_pk_fp8_f32(a, b, 0, false);
    return (unsigned short)(r & 0xffff);
}

// ---------------- fused conversion kernel (R14, verified) ----------------
__global__ void k_cvt_all(const float* __restrict__ x, const float* __restrict__ w,
                          const float* __restrict__ p,
                          __hip_bfloat16* __restrict__ xb,
                          __hip_bfloat16* __restrict__ wT,
                          unsigned char* __restrict__ pT8) {
    __shared__ float tile[32][33];
    const int bid = blockIdx.x;
    const int tid = threadIdx.x;

    if (bid < 1024) {
#pragma unroll
        for (int r = 0; r < 4; ++r) {
            int i = (bid * 4 + r) * 256 + tid;
            float4 v = reinterpret_cast<const float4*>(x)[i];
            union { ushort4 u; __hip_bfloat16 h[4]; } o;
            o.h[0] = __float2bfloat16(v.x);
            o.h[1] = __float2bfloat16(v.y);
            o.h[2] = __float2bfloat16(v.z);
            o.h[3] = __float2bfloat16(v.w);
            reinterpret_cast<ushort4*>(xb)[i] = o.u;
        }
    } else if (bid < 3584) {
        int idx = bid - 1024;              // 2560: t(10) x fb(32) x nb(8)
        int t  = idx >> 8;
        int fb = ((idx >> 3) & 31) * 32;
        int nb = (idx & 7) * 32;
        int tx = tid & 31, ty = tid >> 5;
#pragma unroll
        for (int j = 0; j < 4; ++j) {
            int f = fb + ty + j * 8;
            int n = nb + tx;
            float v = (n < NNODES) ? w[((size_t)t * FEAT + f) * NNODES + n] : 0.f;
            tile[ty + j * 8][tx] = v;
        }
        __syncthreads();
#pragma unroll
        for (int j = 0; j < 4; ++j) {
            int n = nb + ty + j * 8;
            int f = fb + tx;
            wT[((size_t)t * NLEAF + n) * FEAT + f] = __float2bfloat16(tile[tx][ty + j * 8]);
        }
    } else {
        int idx = bid - 3584;              // 2560: kb(80) x cb(32)
        int cb = (idx & 31) * 32;
        int kb = (idx >> 5) * 32;
        int tx = tid & 31, ty = tid >> 5;
#pragma unroll
        for (int j = 0; j < 4; ++j) {
            int k = kb + ty + j * 8;
            int c = cb + tx;
            float v = (c < NCLS) ? p[(size_t)k * NCLS + c] * 409.6f : 0.f;  // 0.1*4096
            tile[ty + j * 8][tx] = v;
        }
        __syncthreads();
        if (tx < 16) {
#pragma unroll
            for (int j = 0; j < 4; ++j) {
                int c = cb + ty + j * 8;
                float f0 = tile[tx * 2][ty + j * 8];
                float f1 = tile[tx * 2 + 1][ty + j * 8];
                *(unsigned short*)(pT8 + (size_t)c * KTOT + kb + tx * 2) = pk_fp8(f0, f1);
            }
        }
    }
}

// ---------------- GEMM1 + sigmoid + routing ----------------
// NEW: A-operand bypasses LDS — loaded global->VGPR one tile ahead (aReg[t&1]).
// A slice (8KB/tile) is L1-resident across the 4 N-waves. LDS holds B only:
// dbuf 2 x 32KB = 64KB. Per-tile LDS traffic 136 -> 96KB.
// Loop: {stageB(t+1) x4; ldA(t+1) x4; WAITVM(8); BAR; B-frags + MFMA; LGKM; BAR}
__global__ __launch_bounds__(512, 4) void k_gemm1_route(
        const __hip_bfloat16* __restrict__ xb,
        const __hip_bfloat16* __restrict__ wT,
        unsigned char* __restrict__ route8) {
    __shared__ __align__(16) char smem[65536];    // 2 x B 32KB; Ds[64][132] f32 reuse

    int wg = blockIdx.x;                          // 640 blocks
    int sw = (wg & 7) * 80 + (wg >> 3);           // 8 XCD x 80 (tree-grouped per XCD)
    const int bm = sw & 63;
    const int tr = sw >> 6;

    const int tid = threadIdx.x;
    const int lane = tid & 63, wid = tid >> 6;
    const int wm = wid >> 2, wn = wid & 3;        // 2M x 4N, wave 32x64
    const int r8 = lane >> 3, c8 = lane & 7;

    f32x4 acc[2][4] = {};

    const __hip_bfloat16* Bg = wT + (size_t)tr * NLEAF * FEAT;

    // A fragment global addresses: [mf][ks], advance by t*128 per tile
    const char* aAddr[2][2];
#pragma unroll
    for (int mf = 0; mf < 2; ++mf)
#pragma unroll
        for (int ks = 0; ks < 2; ++ks) {
            int row = bm * 64 + wm * 32 + mf * 16 + (lane & 15);
            int s   = ks * 4 + (lane >> 4);
            aAddr[mf][ks] = (const char*)xb + (size_t)row * 2048 + s * 16;
        }

    auto stageB = [&](int b, int k0) {            // 4 loads/thread, 32KB
        const int bufB = b * 32768;
#pragma unroll
        for (int q = 0; q < 4; ++q) {
            int row = (wid * 4 + q) * 8 + r8;
            load_lds16(Bg + (size_t)row * FEAT + k0 + ((c8 ^ r8) << 3),
                       smem + bufB + (wid * 4 + q) * 1024);
        }
    };

    bf16x8 aReg[2][2][2];                         // [t&1][mf][ks]

    // prologue: tile 0 in flight (4 B + 4 A = 8 VMEM)
    stageB(0, 0);
#pragma unroll
    for (int mf = 0; mf < 2; ++mf)
#pragma unroll
        for (int ks = 0; ks < 2; ++ks)
            aReg[0][mf][ks] = *(const bf16x8*)(aAddr[mf][ks]);

#pragma unroll
    for (int t = 0; t < 16; ++t) {
        if (t + 1 < 16) {
            stageB((t + 1) & 1, (t + 1) * 64);
#pragma unroll
            for (int mf = 0; mf < 2; ++mf)
#pragma unroll
                for (int ks = 0; ks < 2; ++ks)
                    aReg[(t + 1) & 1][mf][ks] =
                        *(const bf16x8*)(aAddr[mf][ks] + (t + 1) * 128);
            WAITVM(8);                            // tile t's 8 VMEM landed
        } else {
            WAITVM(0);
        }
        BAR();                                    // B tile t visible to all waves

        const char* Bs = smem + (t & 1) * 32768;
#pragma unroll
        for (int ks = 0; ks < 2; ++ks) {
            const int s = ks * 4 + (lane >> 4);
            const int x7 = lane & 7;
            bf16x8 b[4];
#pragma unroll
            for (int nf = 0; nf < 4; ++nf) {
                int row = wn * 64 + nf * 16 + (lane & 15);
                b[nf] = *(const bf16x8*)(Bs + row * 128 + ((s ^ x7) << 4));
            }
#pragma unroll
            for (int mf = 0; mf < 2; ++mf)
#pragma unroll
                for (int nf = 0; nf < 4; ++nf)
                    acc[mf][nf] = __builtin_amdgcn_mfma_f32_16x16x32_bf16(
                        aReg[t & 1][mf][ks], b[nf], acc[mf][nf], 0, 0, 0);
        }
        WAITLGKM();                               // my B reads retired
        BAR();                                    // safe to overwrite buffer t&1
    }

    __syncthreads();                              // buffers dead; reuse as Ds

    // ---- epilogue (verified): sigmoid nodes 0..126 -> Ds; level-7 from regs ----
    float* Ds = (float*)smem;                     // [64][132] fp32 = 33.8KB
    if (wn < 2) {
#pragma unroll
        for (int mf = 0; mf < 2; ++mf)
#pragma unroll
            for (int nf = 0; nf < 4; ++nf) {
                int col = wn * 64 + nf * 16 + (lane & 15);
                if (col < 127) {
#pragma unroll
                    for (int r = 0; r < 4; ++r) {
                        int row = wm * 32 + mf * 16 + (lane >> 4) * 4 + r;
                        float z = acc[mf][nf][r];
                        Ds[row * 132 + col] = 1.f / (1.f + __expf(-z));
                    }
                }
            }
    }
    __syncthreads();
    if (wn >= 1) {
#pragma unroll
        for (int mf = 0; mf < 2; ++mf)
#pragma unroll
            for (int nf = 0; nf < 4; ++nf) {
                int col = wn * 64 + nf * 16 + (lane & 15);
                if (col >= 127 && col <= 254) {
                    int pnode = col - 127;
#pragma unroll
                    for (int r = 0; r < 4; ++r) {
                        int row = wm * 32 + mf * 16 + (lane >> 4) * 4 + r;
                        float prefix = 1.f;
#pragma unroll
                        for (int l = 0; l < 7; ++l) {
                            int node = (1 << l) - 1 + (pnode >> (7 - l));
                            float v = Ds[row * 132 + node];
                            prefix *= (((pnode >> (6 - l)) & 1) == 0) ? v : (1.f - v);
                        }
                        float wv = 1.f / (1.f + __expf(-acc[mf][nf][r]));
                        unsigned short pk = pk_fp8(prefix * wv * 64.f,
                                                   prefix * (1.f - wv) * 64.f);
                        int bb = bm * 64 + row;
                        *(unsigned short*)(route8 + (size_t)bb * KTOT + tr * NLEAF + 2 * pnode) = pk;
                    }
                }
            }
    }
}

// ---------------- GEMM2 (fp8) + clip (R14/R16, verified) ----------------
__global__ __launch_bounds__(512) void k_gemm2(
        const unsigned char* __restrict__ route8,
        const unsigned char* __restrict__ pT8,
        float* __restrict__ out) {
    __shared__ __align__(16) char smem[98304];

    const int wg = blockIdx.x;                    // 256 blocks
    const int sw = (wg & 7) * 32 + (wg >> 3);     // 8 XCD x 32
    const int bm = sw >> 3;
    const int bn = sw & 7;

    const int tid = threadIdx.x;
    const int lane = tid & 63, wid = tid >> 6;
    const int wm = wid >> 2, wn = wid & 3;        // 2M x 4N, wave 64x32

    f32x4 acc[4][2] = {};

    const char* gA[2]; int lA[2];
    const char* gB[2]; int lB[2];
#pragma unroll
    for (int q = 0; q < 2; ++q) {
        int d = q * 512 + tid, R = d >> 3, c = d & 7, gc = c ^ (R & 7);
        gA[q] = (const char*)route8 + (size_t)(bm * 128 + R) * KTOT + gc * 16;
        lA[q] = d * 16;
        gB[q] = (const char*)pT8 + (size_t)(bn * 128 + R) * KTOT + gc * 16;
        lB[q] = 16384 + d * 16;
    }
    const int g = lane >> 4;
    int offA[4][4];                               // [mf][ks]
#pragma unroll
    for (int mf = 0; mf < 4; ++mf)
#pragma unroll
        for (int ks = 0; ks < 4; ++ks) {
            int ra = wm * 64 + mf * 16 + (lane & 15);
            offA[mf][ks] = ra * 128 + (((ks * 2 + (g >> 1)) ^ (ra & 7)) << 4) + (g & 1) * 8;
        }
    int offB[2][4];                               // [nf][ks]
#pragma unroll
    for (int nf = 0; nf < 2; ++nf)
#pragma unroll
        for (int ks = 0; ks < 4; ++ks) {
            int rb = wn * 32 + nf * 16 + (lane & 15);
            offB[nf][ks] = 16384 + rb * 128 + (((ks * 2 + (g >> 1)) ^ (rb & 7)) << 4) + (g & 1) * 8;
        }

    auto stage = [&](int t) {                     // 4 loads/thread; t in BK=128 units
        char* base = smem + (t % 3) * 32768;
#pragma unroll
        for (int q = 0; q < 2; ++q) {
            load_lds16(gA[q] + (size_t)t * 128, base + lA[q]);
            load_lds16(gB[q] + (size_t)t * 128, base + lB[q]);
        }
    };

    stage(0); stage(1);                           // 8 loads in flight

    const int NT = KTOT / 128;                    // 20
#pragma unroll 4
    for (int t = 0; t < NT; ++t) {
        if (t < NT - 1) { WAITVM(4); }            // tile t landed, t+1 flying
        else            { WAITVM(0); }
        BAR();
        if (t + 2 < NT) stage(t + 2);             // slot (t+2)%3 = (t-1)%3: drained

        const char* As = smem + (t % 3) * 32768;
#pragma unroll
        for (int ks = 0; ks < 4; ++ks) {
            long a[4], b[2];
#pragma unroll
            for (int mf = 0; mf < 4; ++mf)
                a[mf] = *(const long*)(As + offA[mf][ks]);
#pragma unroll
            for (int nf = 0; nf < 2; ++nf)
                b[nf] = *(const long*)(As + offB[nf][ks]);
#pragma unroll
            for (int mf = 0; mf < 4; ++mf)
#pragma unroll
                for (int nf = 0; nf < 2; ++nf)
                    acc[mf][nf] = __builtin_amdgcn_mfma_f32_16x16x32_fp8_fp8(
                        a[mf], b[nf], acc[mf][nf], 0, 0, 0);
        }
        WAITLGKM();
        BAR();
    }

    // ---- dequant + clip + masked store (output 1000 wide) ----
#pragma unroll
    for (int mf = 0; mf < 4; ++mf)
#pragma unroll
        for (int nf = 0; nf < 2; ++nf)
#pragma unroll
            for (int r = 0; r < 4; ++r) {
                int row = bm * 128 + wm * 64 + mf * 16 + (lane >> 4) * 4 + r;
                int col = bn * 128 + wn * 32 + nf * 16 + (lane & 15);
                if (col < NCLS) {
                    float v = acc[mf][nf][r] * DEQ;
                    v = fminf(fmaxf(v, 0.f), 1.f);
                    out[(size_t)row * NCLS + col] = v;
                }
            }
}

extern "C" void kernel_launch(void* const* d_in, const int* in_sizes, int n_in,
                              void* d_out, int out_size, void* d_ws, size_t ws_size,
                              hipStream_t stream) {
    const float* x = (const float*)d_in[0];
    const float* w = (const float*)d_in[1];
    const float* p = (const float*)d_in[2];
    float* out = (float*)d_out;
    char* ws = (char*)d_ws;

    __hip_bfloat16* xb     = (__hip_bfloat16*)(ws + OFF_XB);
    __hip_bfloat16* wT     = (__hip_bfloat16*)(ws + OFF_WT);
    unsigned char*  pT8    = (unsigned char*)(ws + OFF_PT);
    unsigned char*  route8 = (unsigned char*)(ws + OFF_RT);

    k_cvt_all<<<6144, 256, 0, stream>>>(x, w, p, xb, wT, pT8);
    k_gemm1_route<<<640, 512, 0, stream>>>(xb, wT, route8);
    k_gemm2<<<256, 512, 0, stream>>>(route8, pT8, out);
}

// Round 18
// 88.212 us; speedup vs baseline: 1.2355x; 1.2355x over previous
//
#include <hip/hip_runtime.h>
#include <hip/hip_bf16.h>

// ---- problem constants ----
#define BATCH   4096
#define FEAT    1024
#define NTREES  10
#define NNODES  255
#define NLEAF   256
#define NCLS    1000
#define KTOT    2560          // NTREES*NLEAF

typedef __attribute__((ext_vector_type(8))) short  bf16x8;
typedef __attribute__((ext_vector_type(4))) float  f32x4;

// fp8 scales: route stored as fp8(route*64); P stored as fp8(P*0.1*4096)
#define DEQ (1.0f / 262144.0f)

// workspace layout (bytes)
#define OFF_XB 0u             // xb bf16 [4096][1024]      8,388,608
#define OFF_WT 8388608u       // wT bf16 [10][256][1024]   5,242,880
#define OFF_PT 13631488u      // pT8 fp8 [1024][2560]      2,621,440
#define OFF_RT 16252928u      // route8 fp8 [4096][2560]  10,485,760

#define WAITVM(N) asm volatile("s_waitcnt vmcnt(" #N ")" ::: "memory")
#define WAITLGKM() asm volatile("s_waitcnt lgkmcnt(0)" ::: "memory")
#define BAR() __builtin_amdgcn_s_barrier()

__device__ __forceinline__ void load_lds16(const void* g, void* l) {
    __builtin_amdgcn_global_load_lds(
        (const __attribute__((address_space(1))) unsigned int*)g,
        (__attribute__((address_space(3))) unsigned int*)l, 16, 0, 0);
}

__device__ __forceinline__ unsigned short pk_fp8(float a, float b) {
    int r = __builtin_amdgcn_cvt_pk_fp8_f32(a, b, 0, false);
    return (unsigned short)(r & 0xffff);
}

// ---------------- fused conversion kernel (R14, verified) ----------------
__global__ void k_cvt_all(const float* __restrict__ x, const float* __restrict__ w,
                          const float* __restrict__ p,
                          __hip_bfloat16* __restrict__ xb,
                          __hip_bfloat16* __restrict__ wT,
                          unsigned char* __restrict__ pT8) {
    __shared__ float tile[32][33];
    const int bid = blockIdx.x;
    const int tid = threadIdx.x;

    if (bid < 1024) {
#pragma unroll
        for (int r = 0; r < 4; ++r) {
            int i = (bid * 4 + r) * 256 + tid;
            float4 v = reinterpret_cast<const float4*>(x)[i];
            union { ushort4 u; __hip_bfloat16 h[4]; } o;
            o.h[0] = __float2bfloat16(v.x);
            o.h[1] = __float2bfloat16(v.y);
            o.h[2] = __float2bfloat16(v.z);
            o.h[3] = __float2bfloat16(v.w);
            reinterpret_cast<ushort4*>(xb)[i] = o.u;
        }
    } else if (bid < 3584) {
        int idx = bid - 1024;              // 2560: t(10) x fb(32) x nb(8)
        int t  = idx >> 8;
        int fb = ((idx >> 3) & 31) * 32;
        int nb = (idx & 7) * 32;
        int tx = tid & 31, ty = tid >> 5;
#pragma unroll
        for (int j = 0; j < 4; ++j) {
            int f = fb + ty + j * 8;
            int n = nb + tx;
            float v = (n < NNODES) ? w[((size_t)t * FEAT + f) * NNODES + n] : 0.f;
            tile[ty + j * 8][tx] = v;
        }
        __syncthreads();
#pragma unroll
        for (int j = 0; j < 4; ++j) {
            int n = nb + ty + j * 8;
            int f = fb + tx;
            wT[((size_t)t * NLEAF + n) * FEAT + f] = __float2bfloat16(tile[tx][ty + j * 8]);
        }
    } else {
        int idx = bid - 3584;              // 2560: kb(80) x cb(32)
        int cb = (idx & 31) * 32;
        int kb = (idx >> 5) * 32;
        int tx = tid & 31, ty = tid >> 5;
#pragma unroll
        for (int j = 0; j < 4; ++j) {
            int k = kb + ty + j * 8;
            int c = cb + tx;
            float v = (c < NCLS) ? p[(size_t)k * NCLS + c] * 409.6f : 0.f;  // 0.1*4096
            tile[ty + j * 8][tx] = v;
        }
        __syncthreads();
        if (tx < 16) {
#pragma unroll
            for (int j = 0; j < 4; ++j) {
                int c = cb + ty + j * 8;
                float f0 = tile[tx * 2][ty + j * 8];
                float f1 = tile[tx * 2 + 1][ty + j * 8];
                *(unsigned short*)(pT8 + (size_t)c * KTOT + kb + tx * 2) = pk_fp8(f0, f1);
            }
        }
    }
}

// ---------------- GEMM1 + sigmoid + routing ----------------
// T3 "minimum 2-phase" single-barrier loop (guide recipe): per K-tile
// {stage(t+1); ds_read all frags; lgkm0; setprio+MFMA; vmcnt(0); BAR}.
// ONE barrier/tile; vmcnt drain overlaps the compute phase. dbuf 2x40KB.
__global__ __launch_bounds__(512, 4) void k_gemm1_route(
        const __hip_bfloat16* __restrict__ xb,
        const __hip_bfloat16* __restrict__ wT,
        unsigned char* __restrict__ route8) {
    __shared__ __align__(16) char smem[81920];    // 2 x (A 8KB + B 32KB); Ds reuse

    int wg = blockIdx.x;                          // 640 blocks
    int sw = (wg & 7) * 80 + (wg >> 3);           // 8 XCD x 80 (tree-grouped per XCD)
    const int bm = sw & 63;
    const int tr = sw >> 6;

    const int tid = threadIdx.x;
    const int lane = tid & 63, wid = tid >> 6;
    const int wm = wid >> 2, wn = wid & 3;        // 2M x 4N, wave 32x64
    const int r8 = lane >> 3, c8 = lane & 7;

    f32x4 acc[2][4] = {};

    const __hip_bfloat16* Ag = xb + (size_t)(bm * 64) * FEAT;
    const __hip_bfloat16* Bg = wT + (size_t)tr * NLEAF * FEAT;

    const int NT = FEAT / 64;                     // 16

    auto stage = [&](int b, int k0) {
        const int bufA = b * 40960;
        const int bufB = bufA + 8192;
        // A: 64 rows x 64 cols = 8KB -> 1 instr/wave
        load_lds16(Ag + (size_t)(wid * 8 + r8) * FEAT + k0 + ((c8 ^ r8) << 3),
                   smem + bufA + wid * 1024);
        // B: 256 rows x 64 cols = 32KB -> 4 instr/wave
#pragma unroll
        for (int q = 0; q < 4; ++q) {
            int row = (wid * 4 + q) * 8 + r8;
            load_lds16(Bg + (size_t)row * FEAT + k0 + ((c8 ^ r8) << 3),
                       smem + bufB + (wid * 4 + q) * 1024);
        }
    };

    // prologue: tile 0 staged and visible
    stage(0, 0);
    WAITVM(0);
    BAR();

    for (int t = 0; t < NT; ++t) {
        if (t + 1 < NT) stage((t + 1) & 1, (t + 1) * 64);   // issue next-tile loads FIRST

        const char* As = smem + (t & 1) * 40960;
        const char* Bs = As + 8192;
        bf16x8 a[2][2], b[2][4];
#pragma unroll
        for (int ks = 0; ks < 2; ++ks) {
            const int s = ks * 4 + (lane >> 4);
            const int x7 = lane & 7;
#pragma unroll
            for (int mf = 0; mf < 2; ++mf) {
                int row = wm * 32 + mf * 16 + (lane & 15);
                a[ks][mf] = *(const bf16x8*)(As + row * 128 + ((s ^ x7) << 4));
            }
#pragma unroll
            for (int nf = 0; nf < 4; ++nf) {
                int row = wn * 64 + nf * 16 + (lane & 15);
                b[ks][nf] = *(const bf16x8*)(Bs + row * 128 + ((s ^ x7) << 4));
            }
        }
        WAITLGKM();
        __builtin_amdgcn_s_setprio(1);
#pragma unroll
        for (int ks = 0; ks < 2; ++ks)
#pragma unroll
            for (int mf = 0; mf < 2; ++mf)
#pragma unroll
                for (int nf = 0; nf < 4; ++nf)
                    acc[mf][nf] = __builtin_amdgcn_mfma_f32_16x16x32_bf16(
                        a[ks][mf], b[ks][nf], acc[mf][nf], 0, 0, 0);
        __builtin_amdgcn_s_setprio(0);
        if (t + 1 < NT) WAITVM(0);                // next tile landed (issued ~full phase ago)
        BAR();                                    // single barrier: reads retired + next visible
    }

    __syncthreads();                              // buffers dead; reuse as Ds

    // ---- epilogue (verified): sigmoid nodes 0..126 -> Ds; level-7 from regs ----
    float* Ds = (float*)smem;                     // [64][132] fp32 = 33.8KB
    if (wn < 2) {
#pragma unroll
        for (int mf = 0; mf < 2; ++mf)
#pragma unroll
            for (int nf = 0; nf < 4; ++nf) {
                int col = wn * 64 + nf * 16 + (lane & 15);
                if (col < 127) {
#pragma unroll
                    for (int r = 0; r < 4; ++r) {
                        int row = wm * 32 + mf * 16 + (lane >> 4) * 4 + r;
                        float z = acc[mf][nf][r];
                        Ds[row * 132 + col] = 1.f / (1.f + __expf(-z));
                    }
                }
            }
    }
    __syncthreads();
    if (wn >= 1) {
#pragma unroll
        for (int mf = 0; mf < 2; ++mf)
#pragma unroll
            for (int nf = 0; nf < 4; ++nf) {
                int col = wn * 64 + nf * 16 + (lane & 15);
                if (col >= 127 && col <= 254) {
                    int pnode = col - 127;
#pragma unroll
                    for (int r = 0; r < 4; ++r) {
                        int row = wm * 32 + mf * 16 + (lane >> 4) * 4 + r;
                        float prefix = 1.f;
#pragma unroll
                        for (int l = 0; l < 7; ++l) {
                            int node = (1 << l) - 1 + (pnode >> (7 - l));
                            float v = Ds[row * 132 + node];
                            prefix *= (((pnode >> (6 - l)) & 1) == 0) ? v : (1.f - v);
                        }
                        float wv = 1.f / (1.f + __expf(-acc[mf][nf][r]));
                        unsigned short pk = pk_fp8(prefix * wv * 64.f,
                                                   prefix * (1.f - wv) * 64.f);
                        int bb = bm * 64 + row;
                        *(unsigned short*)(route8 + (size_t)bb * KTOT + tr * NLEAF + 2 * pnode) = pk;
                    }
                }
            }
    }
}

// ---------------- GEMM2 (fp8) + clip ----------------
// Same single-barrier T3-minimum loop, dbuf 2 x 32KB, BK=128, NT=20.
__global__ __launch_bounds__(512) void k_gemm2(
        const unsigned char* __restrict__ route8,
        const unsigned char* __restrict__ pT8,
        float* __restrict__ out) {
    __shared__ __align__(16) char smem[65536];

    const int wg = blockIdx.x;                    // 256 blocks
    const int sw = (wg & 7) * 32 + (wg >> 3);     // 8 XCD x 32
    const int bm = sw >> 3;
    const int bn = sw & 7;

    const int tid = threadIdx.x;
    const int lane = tid & 63, wid = tid >> 6;
    const int wm = wid >> 2, wn = wid & 3;        // 2M x 4N, wave 64x32

    f32x4 acc[4][2] = {};

    const char* gA[2]; int lA[2];
    const char* gB[2]; int lB[2];
#pragma unroll
    for (int q = 0; q < 2; ++q) {
        int d = q * 512 + tid, R = d >> 3, c = d & 7, gc = c ^ (R & 7);
        gA[q] = (const char*)route8 + (size_t)(bm * 128 + R) * KTOT + gc * 16;
        lA[q] = d * 16;
        gB[q] = (const char*)pT8 + (size_t)(bn * 128 + R) * KTOT + gc * 16;
        lB[q] = 16384 + d * 16;
    }
    const int g = lane >> 4;
    int offA[4][4];                               // [mf][ks]
#pragma unroll
    for (int mf = 0; mf < 4; ++mf)
#pragma unroll
        for (int ks = 0; ks < 4; ++ks) {
            int ra = wm * 64 + mf * 16 + (lane & 15);
            offA[mf][ks] = ra * 128 + (((ks * 2 + (g >> 1)) ^ (ra & 7)) << 4) + (g & 1) * 8;
        }
    int offB[2][4];                               // [nf][ks]
#pragma unroll
    for (int nf = 0; nf < 2; ++nf)
#pragma unroll
        for (int ks = 0; ks < 4; ++ks) {
            int rb = wn * 32 + nf * 16 + (lane & 15);
            offB[nf][ks] = 16384 + rb * 128 + (((ks * 2 + (g >> 1)) ^ (rb & 7)) << 4) + (g & 1) * 8;
        }

    auto stage = [&](int t) {                     // 4 loads/thread; t in BK=128 units
        char* base = smem + (t & 1) * 32768;
#pragma unroll
        for (int q = 0; q < 2; ++q) {
            load_lds16(gA[q] + (size_t)t * 128, base + lA[q]);
            load_lds16(gB[q] + (size_t)t * 128, base + lB[q]);
        }
    };

    // prologue
    stage(0);
    WAITVM(0);
    BAR();

    const int NT = KTOT / 128;                    // 20
    for (int t = 0; t < NT; ++t) {
        if (t + 1 < NT) stage(t + 1);             // issue next-tile loads FIRST

        const char* As = smem + (t & 1) * 32768;
        long a[4][4], b[2][4];
#pragma unroll
        for (int ks = 0; ks < 4; ++ks) {
#pragma unroll
            for (int mf = 0; mf < 4; ++mf)
                a[mf][ks] = *(const long*)(As + offA[mf][ks]);
#pragma unroll
            for (int nf = 0; nf < 2; ++nf)
                b[nf][ks] = *(const long*)(As + offB[nf][ks]);
        }
        WAITLGKM();
        __builtin_amdgcn_s_setprio(1);
#pragma unroll
        for (int ks = 0; ks < 4; ++ks)
#pragma unroll
            for (int mf = 0; mf < 4; ++mf)
#pragma unroll
                for (int nf = 0; nf < 2; ++nf)
                    acc[mf][nf] = __builtin_amdgcn_mfma_f32_16x16x32_fp8_fp8(
                        a[mf][ks], b[nf][ks], acc[mf][nf], 0, 0, 0);
        __builtin_amdgcn_s_setprio(0);
        if (t + 1 < NT) WAITVM(0);
        BAR();
    }

    // ---- dequant + clip + masked store (output 1000 wide) ----
#pragma unroll
    for (int mf = 0; mf < 4; ++mf)
#pragma unroll
        for (int nf = 0; nf < 2; ++nf)
#pragma unroll
            for (int r = 0; r < 4; ++r) {
                int row = bm * 128 + wm * 64 + mf * 16 + (lane >> 4) * 4 + r;
                int col = bn * 128 + wn * 32 + nf * 16 + (lane & 15);
                if (col < NCLS) {
                    float v = acc[mf][nf][r] * DEQ;
                    v = fminf(fmaxf(v, 0.f), 1.f);
                    out[(size_t)row * NCLS + col] = v;
                }
            }
}

extern "C" void kernel_launch(void* const* d_in, const int* in_sizes, int n_in,
                              void* d_out, int out_size, void* d_ws, size_t ws_size,
                              hipStream_t stream) {
    const float* x = (const float*)d_in[0];
    const float* w = (const float*)d_in[1];
    const float* p = (const float*)d_in[2];
    float* out = (float*)d_out;
    char* ws = (char*)d_ws;

    __hip_bfloat16* xb     = (__hip_bfloat16*)(ws + OFF_XB);
    __hip_bfloat16* wT     = (__hip_bfloat16*)(ws + OFF_WT);
    unsigned char*  pT8    = (unsigned char*)(ws + OFF_PT);
    unsigned char*  route8 = (unsigned char*)(ws + OFF_RT);

    k_cvt_all<<<6144, 256, 0, stream>>>(x, w, p, xb, wT, pT8);
    k_gemm1_route<<<640, 512, 0, stream>>>(xb, wT, route8);
    k_gemm2<<<256, 512, 0, stream>>>(route8, pT8, out);
}

// Round 19
// 87.767 us; speedup vs baseline: 1.2418x; 1.0051x over previous
//
#include <hip/hip_runtime.h>
#include <hip/hip_bf16.h>

// ---- problem constants ----
#define BATCH   4096
#define FEAT    1024
#define NTREES  10
#define NNODES  255
#define NLEAF   256
#define NCLS    1000
#define KTOT    2560          // NTREES*NLEAF

typedef __attribute__((ext_vector_type(8))) short  bf16x8;
typedef __attribute__((ext_vector_type(4))) float  f32x4;

// fp8 scales: route stored as fp8(route*64); P stored as fp8(P*0.1*4096)
#define DEQ (1.0f / 262144.0f)

// workspace layout (bytes)
#define OFF_XB 0u             // xb bf16 [4096][1024]      8,388,608
#define OFF_WT 8388608u       // wT bf16 [10][256][1024]   5,242,880
#define OFF_PT 13631488u      // pT8 fp8 [1024][2560]      2,621,440
#define OFF_RT 16252928u      // route8 fp8 [4096][2560]  10,485,760

#define WAITVM(N) asm volatile("s_waitcnt vmcnt(" #N ")" ::: "memory")
#define WAITLGKM() asm volatile("s_waitcnt lgkmcnt(0)" ::: "memory")
#define BAR() __builtin_amdgcn_s_barrier()

__device__ __forceinline__ void load_lds16(const void* g, void* l) {
    __builtin_amdgcn_global_load_lds(
        (const __attribute__((address_space(1))) unsigned int*)g,
        (__attribute__((address_space(3))) unsigned int*)l, 16, 0, 0);
}

__device__ __forceinline__ unsigned short pk_fp8(float a, float b) {
    int r = __builtin_amdgcn_cvt_pk_fp8_f32(a, b, 0, false);
    return (unsigned short)(r & 0xffff);
}

// ---------------- fused conversion kernel (R14/R16, verified) ----------------
__global__ void k_cvt_all(const float* __restrict__ x, const float* __restrict__ w,
                          const float* __restrict__ p,
                          __hip_bfloat16* __restrict__ xb,
                          __hip_bfloat16* __restrict__ wT,
                          unsigned char* __restrict__ pT8) {
    __shared__ float tile[32][33];
    const int bid = blockIdx.x;
    const int tid = threadIdx.x;

    if (bid < 1024) {
#pragma unroll
        for (int r = 0; r < 4; ++r) {
            int i = (bid * 4 + r) * 256 + tid;
            float4 v = reinterpret_cast<const float4*>(x)[i];
            union { ushort4 u; __hip_bfloat16 h[4]; } o;
            o.h[0] = __float2bfloat16(v.x);
            o.h[1] = __float2bfloat16(v.y);
            o.h[2] = __float2bfloat16(v.z);
            o.h[3] = __float2bfloat16(v.w);
            reinterpret_cast<ushort4*>(xb)[i] = o.u;
        }
    } else if (bid < 3584) {
        int idx = bid - 1024;              // 2560: t(10) x fb(32) x nb(8)
        int t  = idx >> 8;
        int fb = ((idx >> 3) & 31) * 32;
        int nb = (idx & 7) * 32;
        int tx = tid & 31, ty = tid >> 5;
#pragma unroll
        for (int j = 0; j < 4; ++j) {
            int f = fb + ty + j * 8;
            int n = nb + tx;
            float v = (n < NNODES) ? w[((size_t)t * FEAT + f) * NNODES + n] : 0.f;
            tile[ty + j * 8][tx] = v;
        }
        __syncthreads();
#pragma unroll
        for (int j = 0; j < 4; ++j) {
            int n = nb + ty + j * 8;
            int f = fb + tx;
            wT[((size_t)t * NLEAF + n) * FEAT + f] = __float2bfloat16(tile[tx][ty + j * 8]);
        }
    } else {
        int idx = bid - 3584;              // 2560: kb(80) x cb(32)
        int cb = (idx & 31) * 32;
        int kb = (idx >> 5) * 32;
        int tx = tid & 31, ty = tid >> 5;
#pragma unroll
        for (int j = 0; j < 4; ++j) {
            int k = kb + ty + j * 8;
            int c = cb + tx;
            float v = (c < NCLS) ? p[(size_t)k * NCLS + c] * 409.6f : 0.f;  // 0.1*4096
            tile[ty + j * 8][tx] = v;
        }
        __syncthreads();
        if (tx < 16) {
#pragma unroll
            for (int j = 0; j < 4; ++j) {
                int c = cb + ty + j * 8;
                float f0 = tile[tx * 2][ty + j * 8];
                float f1 = tile[tx * 2 + 1][ty + j * 8];
                *(unsigned short*)(pT8 + (size_t)c * KTOT + kb + tx * 2) = pk_fp8(f0, f1);
            }
        }
    }
}

// ---------------- GEMM1 + sigmoid + routing (R16, verified best: 45.8us) ----------------
// tile 64(M) x 256(N=one tree), BK=64, 512 thr = 8 waves (2M x 4N, wave 32x64).
// dbuf 2x40KB; loop {stage(t+1); WAITVM(5); BAR; reads+MFMA; LGKM; BAR}.
__global__ __launch_bounds__(512, 4) void k_gemm1_route(
        const __hip_bfloat16* __restrict__ xb,
        const __hip_bfloat16* __restrict__ wT,
        unsigned char* __restrict__ route8) {
    __shared__ __align__(16) char smem[81920];    // 2 x (A 8KB + B 32KB); Ds reuse

    int wg = blockIdx.x;                          // 640 blocks
    int sw = (wg & 7) * 80 + (wg >> 3);           // 8 XCD x 80 (tree-grouped per XCD)
    const int bm = sw & 63;
    const int tr = sw >> 6;

    const int tid = threadIdx.x;
    const int lane = tid & 63, wid = tid >> 6;
    const int wm = wid >> 2, wn = wid & 3;        // 2M x 4N, wave 32x64
    const int r8 = lane >> 3, c8 = lane & 7;

    f32x4 acc[2][4] = {};

    const __hip_bfloat16* Ag = xb + (size_t)(bm * 64) * FEAT;
    const __hip_bfloat16* Bg = wT + (size_t)tr * NLEAF * FEAT;

    const int NT = FEAT / 64;                     // 16

    auto stage = [&](int b, int k0) {
        const int bufA = b * 40960;
        const int bufB = bufA + 8192;
        load_lds16(Ag + (size_t)(wid * 8 + r8) * FEAT + k0 + ((c8 ^ r8) << 3),
                   smem + bufA + wid * 1024);
#pragma unroll
        for (int q = 0; q < 4; ++q) {
            int row = (wid * 4 + q) * 8 + r8;
            load_lds16(Bg + (size_t)row * FEAT + k0 + ((c8 ^ r8) << 3),
                       smem + bufB + (wid * 4 + q) * 1024);
        }
    };

    stage(0, 0);                                  // 5 loads in flight

    for (int t = 0; t < NT; ++t) {
        if (t + 1 < NT) { stage((t + 1) & 1, (t + 1) * 64); WAITVM(5); }
        else            { WAITVM(0); }
        BAR();                                    // all waves' tile-t loads visible

        const char* As = smem + (t & 1) * 40960;
        const char* Bs = As + 8192;
#pragma unroll
        for (int ks = 0; ks < 2; ++ks) {
            const int s = ks * 4 + (lane >> 4);
            const int x7 = lane & 7;
            bf16x8 a[2], b[4];
#pragma unroll
            for (int mf = 0; mf < 2; ++mf) {
                int row = wm * 32 + mf * 16 + (lane & 15);
                a[mf] = *(const bf16x8*)(As + row * 128 + ((s ^ x7) << 4));
            }
#pragma unroll
            for (int nf = 0; nf < 4; ++nf) {
                int row = wn * 64 + nf * 16 + (lane & 15);
                b[nf] = *(const bf16x8*)(Bs + row * 128 + ((s ^ x7) << 4));
            }
#pragma unroll
            for (int mf = 0; mf < 2; ++mf)
#pragma unroll
                for (int nf = 0; nf < 4; ++nf)
                    acc[mf][nf] = __builtin_amdgcn_mfma_f32_16x16x32_bf16(
                        a[mf], b[nf], acc[mf][nf], 0, 0, 0);
        }
        WAITLGKM();                               // my reads retired
        BAR();                                    // safe to overwrite
    }

    __syncthreads();                              // buffers dead; reuse as Ds

    // ---- epilogue (verified): sigmoid nodes 0..126 -> Ds; level-7 from regs ----
    float* Ds = (float*)smem;                     // [64][132] fp32 = 33.8KB
    if (wn < 2) {
#pragma unroll
        for (int mf = 0; mf < 2; ++mf)
#pragma unroll
            for (int nf = 0; nf < 4; ++nf) {
                int col = wn * 64 + nf * 16 + (lane & 15);
                if (col < 127) {
#pragma unroll
                    for (int r = 0; r < 4; ++r) {
                        int row = wm * 32 + mf * 16 + (lane >> 4) * 4 + r;
                        float z = acc[mf][nf][r];
                        Ds[row * 132 + col] = 1.f / (1.f + __expf(-z));
                    }
                }
            }
    }
    __syncthreads();
    if (wn >= 1) {
#pragma unroll
        for (int mf = 0; mf < 2; ++mf)
#pragma unroll
            for (int nf = 0; nf < 4; ++nf) {
                int col = wn * 64 + nf * 16 + (lane & 15);
                if (col >= 127 && col <= 254) {
                    int pnode = col - 127;
#pragma unroll
                    for (int r = 0; r < 4; ++r) {
                        int row = wm * 32 + mf * 16 + (lane >> 4) * 4 + r;
                        float prefix = 1.f;
#pragma unroll
                        for (int l = 0; l < 7; ++l) {
                            int node = (1 << l) - 1 + (pnode >> (7 - l));
                            float v = Ds[row * 132 + node];
                            prefix *= (((pnode >> (6 - l)) & 1) == 0) ? v : (1.f - v);
                        }
                        float wv = 1.f / (1.f + __expf(-acc[mf][nf][r]));
                        unsigned short pk = pk_fp8(prefix * wv * 64.f,
                                                   prefix * (1.f - wv) * 64.f);
                        int bb = bm * 64 + row;
                        *(unsigned short*)(route8 + (size_t)bb * KTOT + tr * NLEAF + 2 * pnode) = pk;
                    }
                }
            }
    }
}

// ---------------- GEMM2 (fp8) + clip ----------------
// NEW: 1024 threads = 16 waves (4M x 4N, wave 32x32) on the same 128x128 tile,
// grid 256 -> 4 waves/SIMD for latency hiding (was 2). ring-3 x 32KB = 96KB,
// depth-2 counted WAITVM(2). Staging: 1 A + 1 B chunk per thread.
__global__ __launch_bounds__(1024) void k_gemm2(
        const unsigned char* __restrict__ route8,
        const unsigned char* __restrict__ pT8,
        float* __restrict__ out) {
    __shared__ __align__(16) char smem[98304];

    const int wg = blockIdx.x;                    // 256 blocks
    const int sw = (wg & 7) * 32 + (wg >> 3);     // 8 XCD x 32
    const int bm = sw >> 3;
    const int bn = sw & 7;

    const int tid = threadIdx.x;
    const int lane = tid & 63, wid = tid >> 6;    // 16 waves
    const int wm = wid >> 2, wn = wid & 3;        // 4M x 4N, wave 32x32

    f32x4 acc[2][2] = {};

    // staging: A 128 rows x 128B = 16KB (1024 chunks) -> 1 chunk/thread; B same
    const char* gA; const char* gB; int lA, lB;
    {
        int d = tid, R = d >> 3, c = d & 7, gc = c ^ (R & 7);
        gA = (const char*)route8 + (size_t)(bm * 128 + R) * KTOT + gc * 16;
        lA = d * 16;
        gB = (const char*)pT8 + (size_t)(bn * 128 + R) * KTOT + gc * 16;
        lB = 16384 + d * 16;
    }
    const int g = lane >> 4;
    int offA[2][4];                               // [mf][ks]
#pragma unroll
    for (int mf = 0; mf < 2; ++mf)
#pragma unroll
        for (int ks = 0; ks < 4; ++ks) {
            int ra = wm * 32 + mf * 16 + (lane & 15);
            offA[mf][ks] = ra * 128 + (((ks * 2 + (g >> 1)) ^ (ra & 7)) << 4) + (g & 1) * 8;
        }
    int offB[2][4];                               // [nf][ks]
#pragma unroll
    for (int nf = 0; nf < 2; ++nf)
#pragma unroll
        for (int ks = 0; ks < 4; ++ks) {
            int rb = wn * 32 + nf * 16 + (lane & 15);
            offB[nf][ks] = 16384 + rb * 128 + (((ks * 2 + (g >> 1)) ^ (rb & 7)) << 4) + (g & 1) * 8;
        }

    auto stage = [&](int t) {                     // 2 loads/thread; t in BK=128 units
        char* base = smem + (t % 3) * 32768;
        load_lds16(gA + (size_t)t * 128, base + lA);
        load_lds16(gB + (size_t)t * 128, base + lB);
    };

    stage(0); stage(1);                           // 4 loads in flight

    const int NT = KTOT / 128;                    // 20
#pragma unroll 4
    for (int t = 0; t < NT; ++t) {
        if (t < NT - 1) { WAITVM(2); }            // tile t landed, t+1 flying
        else            { WAITVM(0); }
        BAR();
        if (t + 2 < NT) stage(t + 2);             // slot (t+2)%3 = (t-1)%3: drained

        const char* As = smem + (t % 3) * 32768;
#pragma unroll
        for (int ks = 0; ks < 4; ++ks) {
            long a[2], b[2];
#pragma unroll
            for (int mf = 0; mf < 2; ++mf)
                a[mf] = *(const long*)(As + offA[mf][ks]);
#pragma unroll
            for (int nf = 0; nf < 2; ++nf)
                b[nf] = *(const long*)(As + offB[nf][ks]);
#pragma unroll
            for (int mf = 0; mf < 2; ++mf)
#pragma unroll
                for (int nf = 0; nf < 2; ++nf)
                    acc[mf][nf] = __builtin_amdgcn_mfma_f32_16x16x32_fp8_fp8(
                        a[mf], b[nf], acc[mf][nf], 0, 0, 0);
        }
        WAITLGKM();                               // my reads of slot t%3 retired
        BAR();                                    // safe for stage(t+3) next iter
    }

    // ---- dequant + clip + masked store (output 1000 wide) ----
#pragma unroll
    for (int mf = 0; mf < 2; ++mf)
#pragma unroll
        for (int nf = 0; nf < 2; ++nf)
#pragma unroll
            for (int r = 0; r < 4; ++r) {
                int row = bm * 128 + wm * 32 + mf * 16 + (lane >> 4) * 4 + r;
                int col = bn * 128 + wn * 32 + nf * 16 + (lane & 15);
                if (col < NCLS) {
                    float v = acc[mf][nf][r] * DEQ;
                    v = fminf(fmaxf(v, 0.f), 1.f);
                    out[(size_t)row * NCLS + col] = v;
                }
            }
}

extern "C" void kernel_launch(void* const* d_in, const int* in_sizes, int n_in,
                              void* d_out, int out_size, void* d_ws, size_t ws_size,
                              hipStream_t stream) {
    const float* x = (const float*)d_in[0];
    const float* w = (const float*)d_in[1];
    const float* p = (const float*)d_in[2];
    float* out = (float*)d_out;
    char* ws = (char*)d_ws;

    __hip_bfloat16* xb     = (__hip_bfloat16*)(ws + OFF_XB);
    __hip_bfloat16* wT     = (__hip_bfloat16*)(ws + OFF_WT);
    unsigned char*  pT8    = (unsigned char*)(ws + OFF_PT);
    unsigned char*  route8 = (unsigned char*)(ws + OFF_RT);

    k_cvt_all<<<6144, 256, 0, stream>>>(x, w, p, xb, wT, pT8);
    k_gemm1_route<<<640, 512, 0, stream>>>(xb, wT, route8);
    k_gemm2<<<256, 1024, 0, stream>>>(route8, pT8, out);
}

// Round 20
// 84.070 us; speedup vs baseline: 1.2964x; 1.0440x over previous
//
#include <hip/hip_runtime.h>
#include <hip/hip_bf16.h>

// ---- problem constants ----
#define BATCH   4096
#define FEAT    1024
#define NTREES  10
#define NNODES  255
#define NLEAF   256
#define NCLS    1000
#define KTOT    2560          // NTREES*NLEAF

typedef __attribute__((ext_vector_type(8))) short  bf16x8;
typedef __attribute__((ext_vector_type(4))) float  f32x4;

// fp8 scales: route stored as fp8(route*64); P stored as fp8(P*0.1*4096)
#define DEQ (1.0f / 262144.0f)

// workspace layout (bytes)
#define OFF_XB 0u             // xb bf16 [4096][1024]      8,388,608
#define OFF_WT 8388608u       // wT bf16 [10][256][1024]   5,242,880
#define OFF_PT 13631488u      // pT8 fp8 [1024][2560]      2,621,440
#define OFF_RT 16252928u      // route8 fp8 [4096][2560]  10,485,760

#define WAITVM(N) asm volatile("s_waitcnt vmcnt(" #N ")" ::: "memory")
#define WAITLGKM() asm volatile("s_waitcnt lgkmcnt(0)" ::: "memory")
#define BAR() __builtin_amdgcn_s_barrier()

__device__ __forceinline__ void load_lds16(const void* g, void* l) {
    __builtin_amdgcn_global_load_lds(
        (const __attribute__((address_space(1))) unsigned int*)g,
        (__attribute__((address_space(3))) unsigned int*)l, 16, 0, 0);
}

__device__ __forceinline__ unsigned short pk_fp8(float a, float b) {
    int r = __builtin_amdgcn_cvt_pk_fp8_f32(a, b, 0, false);
    return (unsigned short)(r & 0xffff);
}

// ---------------- fused conversion kernel (R14/R16, verified; ~HBM ceiling) ----------------
__global__ void k_cvt_all(const float* __restrict__ x, const float* __restrict__ w,
                          const float* __restrict__ p,
                          __hip_bfloat16* __restrict__ xb,
                          __hip_bfloat16* __restrict__ wT,
                          unsigned char* __restrict__ pT8) {
    __shared__ float tile[32][33];
    const int bid = blockIdx.x;
    const int tid = threadIdx.x;

    if (bid < 1024) {
#pragma unroll
        for (int r = 0; r < 4; ++r) {
            int i = (bid * 4 + r) * 256 + tid;
            float4 v = reinterpret_cast<const float4*>(x)[i];
            union { ushort4 u; __hip_bfloat16 h[4]; } o;
            o.h[0] = __float2bfloat16(v.x);
            o.h[1] = __float2bfloat16(v.y);
            o.h[2] = __float2bfloat16(v.z);
            o.h[3] = __float2bfloat16(v.w);
            reinterpret_cast<ushort4*>(xb)[i] = o.u;
        }
    } else if (bid < 3584) {
        int idx = bid - 1024;              // 2560: t(10) x fb(32) x nb(8)
        int t  = idx >> 8;
        int fb = ((idx >> 3) & 31) * 32;
        int nb = (idx & 7) * 32;
        int tx = tid & 31, ty = tid >> 5;
#pragma unroll
        for (int j = 0; j < 4; ++j) {
            int f = fb + ty + j * 8;
            int n = nb + tx;
            float v = (n < NNODES) ? w[((size_t)t * FEAT + f) * NNODES + n] : 0.f;
            tile[ty + j * 8][tx] = v;
        }
        __syncthreads();
#pragma unroll
        for (int j = 0; j < 4; ++j) {
            int n = nb + ty + j * 8;
            int f = fb + tx;
            wT[((size_t)t * NLEAF + n) * FEAT + f] = __float2bfloat16(tile[tx][ty + j * 8]);
        }
    } else {
        int idx = bid - 3584;              // 2560: kb(80) x cb(32)
        int cb = (idx & 31) * 32;
        int kb = (idx >> 5) * 32;
        int tx = tid & 31, ty = tid >> 5;
#pragma unroll
        for (int j = 0; j < 4; ++j) {
            int k = kb + ty + j * 8;
            int c = cb + tx;
            float v = (c < NCLS) ? p[(size_t)k * NCLS + c] * 409.6f : 0.f;  // 0.1*4096
            tile[ty + j * 8][tx] = v;
        }
        __syncthreads();
        if (tx < 16) {
#pragma unroll
            for (int j = 0; j < 4; ++j) {
                int c = cb + ty + j * 8;
                float f0 = tile[tx * 2][ty + j * 8];
                float f1 = tile[tx * 2 + 1][ty + j * 8];
                *(unsigned short*)(pT8 + (size_t)c * KTOT + kb + tx * 2) = pk_fp8(f0, f1);
            }
        }
    }
}

// ---------------- GEMM1 + sigmoid + routing (R16, verified best: 45.8us) ----------------
// tile 64(M) x 256(N=one tree), BK=64, 512 thr = 8 waves (2M x 4N, wave 32x64).
// dbuf 2x40KB; loop {stage(t+1); WAITVM(5); BAR; reads+MFMA; LGKM; BAR}.
__global__ __launch_bounds__(512, 4) void k_gemm1_route(
        const __hip_bfloat16* __restrict__ xb,
        const __hip_bfloat16* __restrict__ wT,
        unsigned char* __restrict__ route8) {
    __shared__ __align__(16) char smem[81920];    // 2 x (A 8KB + B 32KB); Ds reuse

    int wg = blockIdx.x;                          // 640 blocks
    int sw = (wg & 7) * 80 + (wg >> 3);           // 8 XCD x 80 (tree-grouped per XCD)
    const int bm = sw & 63;
    const int tr = sw >> 6;

    const int tid = threadIdx.x;
    const int lane = tid & 63, wid = tid >> 6;
    const int wm = wid >> 2, wn = wid & 3;        // 2M x 4N, wave 32x64
    const int r8 = lane >> 3, c8 = lane & 7;

    f32x4 acc[2][4] = {};

    const __hip_bfloat16* Ag = xb + (size_t)(bm * 64) * FEAT;
    const __hip_bfloat16* Bg = wT + (size_t)tr * NLEAF * FEAT;

    const int NT = FEAT / 64;                     // 16

    auto stage = [&](int b, int k0) {
        const int bufA = b * 40960;
        const int bufB = bufA + 8192;
        load_lds16(Ag + (size_t)(wid * 8 + r8) * FEAT + k0 + ((c8 ^ r8) << 3),
                   smem + bufA + wid * 1024);
#pragma unroll
        for (int q = 0; q < 4; ++q) {
            int row = (wid * 4 + q) * 8 + r8;
            load_lds16(Bg + (size_t)row * FEAT + k0 + ((c8 ^ r8) << 3),
                       smem + bufB + (wid * 4 + q) * 1024);
        }
    };

    stage(0, 0);                                  // 5 loads in flight

    for (int t = 0; t < NT; ++t) {
        if (t + 1 < NT) { stage((t + 1) & 1, (t + 1) * 64); WAITVM(5); }
        else            { WAITVM(0); }
        BAR();                                    // all waves' tile-t loads visible

        const char* As = smem + (t & 1) * 40960;
        const char* Bs = As + 8192;
#pragma unroll
        for (int ks = 0; ks < 2; ++ks) {
            const int s = ks * 4 + (lane >> 4);
            const int x7 = lane & 7;
            bf16x8 a[2], b[4];
#pragma unroll
            for (int mf = 0; mf < 2; ++mf) {
                int row = wm * 32 + mf * 16 + (lane & 15);
                a[mf] = *(const bf16x8*)(As + row * 128 + ((s ^ x7) << 4));
            }
#pragma unroll
            for (int nf = 0; nf < 4; ++nf) {
                int row = wn * 64 + nf * 16 + (lane & 15);
                b[nf] = *(const bf16x8*)(Bs + row * 128 + ((s ^ x7) << 4));
            }
#pragma unroll
            for (int mf = 0; mf < 2; ++mf)
#pragma unroll
                for (int nf = 0; nf < 4; ++nf)
                    acc[mf][nf] = __builtin_amdgcn_mfma_f32_16x16x32_bf16(
                        a[mf], b[nf], acc[mf][nf], 0, 0, 0);
        }
        WAITLGKM();                               // my reads retired
        BAR();                                    // safe to overwrite
    }

    __syncthreads();                              // buffers dead; reuse as Ds

    // ---- epilogue (verified): sigmoid nodes 0..126 -> Ds; level-7 from regs ----
    float* Ds = (float*)smem;                     // [64][132] fp32 = 33.8KB
    if (wn < 2) {
#pragma unroll
        for (int mf = 0; mf < 2; ++mf)
#pragma unroll
            for (int nf = 0; nf < 4; ++nf) {
                int col = wn * 64 + nf * 16 + (lane & 15);
                if (col < 127) {
#pragma unroll
                    for (int r = 0; r < 4; ++r) {
                        int row = wm * 32 + mf * 16 + (lane >> 4) * 4 + r;
                        float z = acc[mf][nf][r];
                        Ds[row * 132 + col] = 1.f / (1.f + __expf(-z));
                    }
                }
            }
    }
    __syncthreads();
    if (wn >= 1) {
#pragma unroll
        for (int mf = 0; mf < 2; ++mf)
#pragma unroll
            for (int nf = 0; nf < 4; ++nf) {
                int col = wn * 64 + nf * 16 + (lane & 15);
                if (col >= 127 && col <= 254) {
                    int pnode = col - 127;
#pragma unroll
                    for (int r = 0; r < 4; ++r) {
                        int row = wm * 32 + mf * 16 + (lane >> 4) * 4 + r;
                        float prefix = 1.f;
#pragma unroll
                        for (int l = 0; l < 7; ++l) {
                            int node = (1 << l) - 1 + (pnode >> (7 - l));
                            float v = Ds[row * 132 + node];
                            prefix *= (((pnode >> (6 - l)) & 1) == 0) ? v : (1.f - v);
                        }
                        float wv = 1.f / (1.f + __expf(-acc[mf][nf][r]));
                        unsigned short pk = pk_fp8(prefix * wv * 64.f,
                                                   prefix * (1.f - wv) * 64.f);
                        int bb = bm * 64 + row;
                        *(unsigned short*)(route8 + (size_t)bb * KTOT + tr * NLEAF + 2 * pnode) = pk;
                    }
                }
            }
    }
}

// ---------------- GEMM2 (fp8) + clip (R16, verified best) ----------------
// tile 128x128 (grid 256 = 1 round), BK=128, 512 thr = 8 waves (2M x 4N,
// wave 64x32). ring-3 x 32KB = 96KB, depth-2 counted WAITVM(4). NT=20.
__global__ __launch_bounds__(512) void k_gemm2(
        const unsigned char* __restrict__ route8,
        const unsigned char* __restrict__ pT8,
        float* __restrict__ out) {
    __shared__ __align__(16) char smem[98304];

    const int wg = blockIdx.x;                    // 256 blocks
    const int sw = (wg & 7) * 32 + (wg >> 3);     // 8 XCD x 32
    const int bm = sw >> 3;
    const int bn = sw & 7;

    const int tid = threadIdx.x;
    const int lane = tid & 63, wid = tid >> 6;
    const int wm = wid >> 2, wn = wid & 3;        // 2M x 4N, wave 64x32

    f32x4 acc[4][2] = {};

    const char* gA[2]; int lA[2];
    const char* gB[2]; int lB[2];
#pragma unroll
    for (int q = 0; q < 2; ++q) {
        int d = q * 512 + tid, R = d >> 3, c = d & 7, gc = c ^ (R & 7);
        gA[q] = (const char*)route8 + (size_t)(bm * 128 + R) * KTOT + gc * 16;
        lA[q] = d * 16;
        gB[q] = (const char*)pT8 + (size_t)(bn * 128 + R) * KTOT + gc * 16;
        lB[q] = 16384 + d * 16;
    }
    const int g = lane >> 4;
    int offA[4][4];                               // [mf][ks]
#pragma unroll
    for (int mf = 0; mf < 4; ++mf)
#pragma unroll
        for (int ks = 0; ks < 4; ++ks) {
            int ra = wm * 64 + mf * 16 + (lane & 15);
            offA[mf][ks] = ra * 128 + (((ks * 2 + (g >> 1)) ^ (ra & 7)) << 4) + (g & 1) * 8;
        }
    int offB[2][4];                               // [nf][ks]
#pragma unroll
    for (int nf = 0; nf < 2; ++nf)
#pragma unroll
        for (int ks = 0; ks < 4; ++ks) {
            int rb = wn * 32 + nf * 16 + (lane & 15);
            offB[nf][ks] = 16384 + rb * 128 + (((ks * 2 + (g >> 1)) ^ (rb & 7)) << 4) + (g & 1) * 8;
        }

    auto stage = [&](int t) {                     // 4 loads/thread; t in BK=128 units
        char* base = smem + (t % 3) * 32768;
#pragma unroll
        for (int q = 0; q < 2; ++q) {
            load_lds16(gA[q] + (size_t)t * 128, base + lA[q]);
            load_lds16(gB[q] + (size_t)t * 128, base + lB[q]);
        }
    };

    stage(0); stage(1);                           // 8 loads in flight

    const int NT = KTOT / 128;                    // 20
#pragma unroll 4
    for (int t = 0; t < NT; ++t) {
        if (t < NT - 1) { WAITVM(4); }            // tile t landed, t+1 flying
        else            { WAITVM(0); }
        BAR();
        if (t + 2 < NT) stage(t + 2);             // slot (t+2)%3 = (t-1)%3: drained

        const char* As = smem + (t % 3) * 32768;
#pragma unroll
        for (int ks = 0; ks < 4; ++ks) {
            long a[4], b[2];
#pragma unroll
            for (int mf = 0; mf < 4; ++mf)
                a[mf] = *(const long*)(As + offA[mf][ks]);
#pragma unroll
            for (int nf = 0; nf < 2; ++nf)
                b[nf] = *(const long*)(As + offB[nf][ks]);
#pragma unroll
            for (int mf = 0; mf < 4; ++mf)
#pragma unroll
                for (int nf = 0; nf < 2; ++nf)
                    acc[mf][nf] = __builtin_amdgcn_mfma_f32_16x16x32_fp8_fp8(
                        a[mf], b[nf], acc[mf][nf], 0, 0, 0);
        }
        WAITLGKM();                               // my reads of slot t%3 retired
        BAR();                                    // safe for stage(t+3) next iter
    }

    // ---- dequant + clip + masked store (output 1000 wide) ----
#pragma unroll
    for (int mf = 0; mf < 4; ++mf)
#pragma unroll
        for (int nf = 0; nf < 2; ++nf)
#pragma unroll
            for (int r = 0; r < 4; ++r) {
                int row = bm * 128 + wm * 64 + mf * 16 + (lane >> 4) * 4 + r;
                int col = bn * 128 + wn * 32 + nf * 16 + (lane & 15);
                if (col < NCLS) {
                    float v = acc[mf][nf][r] * DEQ;
                    v = fminf(fmaxf(v, 0.f), 1.f);
                    out[(size_t)row * NCLS + col] = v;
                }
            }
}

extern "C" void kernel_launch(void* const* d_in, const int* in_sizes, int n_in,
                              void* d_out, int out_size, void* d_ws, size_t ws_size,
                              hipStream_t stream) {
    const float* x = (const float*)d_in[0];
    const float* w = (const float*)d_in[1];
    const float* p = (const float*)d_in[2];
    float* out = (float*)d_out;
    char* ws = (char*)d_ws;

    __hip_bfloat16* xb     = (__hip_bfloat16*)(ws + OFF_XB);
    __hip_bfloat16* wT     = (__hip_bfloat16*)(ws + OFF_WT);
    unsigned char*  pT8    = (unsigned char*)(ws + OFF_PT);
    unsigned char*  route8 = (unsigned char*)(ws + OFF_RT);

    k_cvt_all<<<6144, 256, 0, stream>>>(x, w, p, xb, wT, pT8);
    k_gemm1_route<<<640, 512, 0, stream>>>(xb, wT, route8);
    k_gemm2<<<256, 512, 0, stream>>>(route8, pT8, out);
}